// Round 1
// baseline (130.080 us; speedup 1.0000x reference)
//
#include <hip/hip_runtime.h>

#define NHEAD 16
#define TDIM 2048
#define SDIM 2048
#define KMAX 4

// ---------------------------------------------------------------------------
// Kernel A: bulk identity copy of the whole tensor, vectorized float4.
// ---------------------------------------------------------------------------
__global__ void bulk_copy_kernel(const float4* __restrict__ in,
                                 float4* __restrict__ out, long n4) {
    long i = (long)blockIdx.x * blockDim.x + threadIdx.x;
    long stride = (long)gridDim.x * blockDim.x;
    for (; i < n4; i += stride) {
        out[i] = in[i];
    }
}

// ---------------------------------------------------------------------------
// Kernel B: decision + last-row rewrite. One block, 1024 threads = 16 waves.
// Wave h computes argmax (first-occurrence tie-break) of head h's last row.
// Thread 0 then does the 16x16 vote count and decides replacement; all
// threads rewrite the 16 last rows of the output from the INPUT.
// ---------------------------------------------------------------------------
__global__ void __launch_bounds__(1024)
decide_apply_kernel(const float* __restrict__ in, float* __restrict__ out) {
    __shared__ int s_cand[NHEAD];
    __shared__ int s_replace[NHEAD];
    __shared__ int s_sampled;

    const int tid  = threadIdx.x;
    const int head = tid >> 6;   // 16 waves -> 16 heads
    const int lane = tid & 63;

    const size_t last_off = (size_t)(TDIM - 1) * SDIM;

    // --- per-head argmax over S, first-occurrence tie-break ---
    const float* row = in + (size_t)head * TDIM * SDIM + last_off;
    float best = -1.0f;          // inputs are uniform [0,1)
    int   bidx = 1 << 30;
    for (int s = lane; s < SDIM; s += 64) {
        float v = row[s];
        if (v > best || (v == best && s < bidx)) { best = v; bidx = s; }
    }
    #pragma unroll
    for (int off = 32; off > 0; off >>= 1) {
        float ov = __shfl_down(best, off);
        int   oi = __shfl_down(bidx, off);
        if (ov > best || (ov == best && oi < bidx)) { best = ov; bidx = oi; }
    }
    if (lane == 0) s_cand[head] = bidx;
    __syncthreads();

    // --- serial decision on thread 0 (16x16 comparisons, trivial) ---
    if (tid == 0) {
        int cnt[NHEAD];
        int maxv = 0;
        for (int h = 0; h < NHEAD; ++h) {
            int c = 0;
            for (int g = 0; g < NHEAD; ++g) c += (s_cand[g] == s_cand[h]);
            cnt[h] = c;
            if (c > maxv) maxv = c;
        }
        // counting[cand[h]] == cnt[h]; max of counting == maxv (zeros elsewhere)
        int sampled = 0;
        for (int h = NHEAD - 1; h >= 0; --h)
            if (cnt[h] == maxv) sampled = h;       // first head with mask true
        const bool merge = (maxv <= KMAX);
        for (int h = 0; h < NHEAD; ++h)
            s_replace[h] = (merge && cnt[h] == maxv) ? 1 : 0;
        s_sampled = sampled;
    }
    __syncthreads();

    const int sampled = s_sampled;

    // --- rewrite the 16 last rows (16 x 2048 floats) from the input ---
    for (int idx = tid; idx < NHEAD * SDIM; idx += 1024) {
        const int h = idx >> 11;        // / SDIM
        const int s = idx & (SDIM - 1); // % SDIM
        const int src_h = s_replace[h] ? sampled : h;
        out[(size_t)h * TDIM * SDIM + last_off + s] =
            in[(size_t)src_h * TDIM * SDIM + last_off + s];
    }
}

extern "C" void kernel_launch(void* const* d_in, const int* in_sizes, int n_in,
                              void* d_out, int out_size, void* d_ws, size_t ws_size,
                              hipStream_t stream) {
    const float* in = (const float*)d_in[0];
    float* out = (float*)d_out;

    const long n  = (long)NHEAD * TDIM * SDIM;  // 67,108,864 floats
    const long n4 = n / 4;                      // 16,777,216 float4

    bulk_copy_kernel<<<2048, 256, 0, stream>>>((const float4*)in, (float4*)out, n4);
    decide_apply_kernel<<<1, 1024, 0, stream>>>(in, out);
}

// Round 2
// 116.495 us; speedup vs baseline: 1.1166x; 1.1166x over previous
//
#include <hip/hip_runtime.h>

#define NHEAD 16
#define TDIM 2048
#define SDIM 2048
#define KMAX 4

#define S4    (SDIM / 4)            // 512 float4 per row
#define HEAD4 (TDIM * S4)           // 1048576 float4 per head (power of 2)
#define COPY4 ((TDIM - 1) * S4)     // 1048064 float4 per head, excluding last row
#define N4    (NHEAD * HEAD4)       // 16777216 float4 total
#define NCOPYBLK 2048
#define BLKSZ 256

// One fused kernel:
//  - blocks [0, NCOPYBLK): grid-stride float4 copy of everything EXCEPT each
//    head's last row (power-of-2 head stride -> skip test is a mask compare).
//  - block NCOPYBLK: computes per-head argmax of the last rows, the vote/merge
//    decision, and writes all 16 last rows. Reads only `in`, so it is fully
//    independent of the copy blocks -> runs concurrently, latency hidden.
__global__ void __launch_bounds__(BLKSZ)
fused_policy_kernel(const float4* __restrict__ in, float4* __restrict__ out) {
    const int tid = threadIdx.x;

    if (blockIdx.x < NCOPYBLK) {
        // ---- bulk copy, skipping last rows ----
        unsigned i = blockIdx.x * BLKSZ + tid;
        const unsigned stride = NCOPYBLK * BLKSZ;
        for (; i < N4; i += stride) {
            if ((i & (HEAD4 - 1)) < COPY4) {
                out[i] = in[i];
            }
        }
        return;
    }

    // ---- decider block: 256 threads, 16 threads per head ----
    __shared__ int s_cand[NHEAD];
    __shared__ int s_replace[NHEAD];
    __shared__ int s_sampled;

    const int head = tid >> 4;    // 16 groups of 16 threads
    const int l16  = tid & 15;

    const float4* row = in + (size_t)head * HEAD4 + COPY4;  // head's last row

    // per-head argmax, first-occurrence tie-break (matches jnp.argmax)
    float best = -1.0f;           // inputs are uniform [0,1)
    int   bidx = 1 << 30;
    for (int f = l16; f < S4; f += 16) {
        float4 v = row[f];
        const int e = f * 4;
        if (v.x > best) { best = v.x; bidx = e + 0; }
        if (v.y > best) { best = v.y; bidx = e + 1; }
        if (v.z > best) { best = v.z; bidx = e + 2; }
        if (v.w > best) { best = v.w; bidx = e + 3; }
    }
    #pragma unroll
    for (int off = 8; off > 0; off >>= 1) {
        float ov = __shfl_down(best, off, 16);
        int   oi = __shfl_down(bidx, off, 16);
        if (ov > best || (ov == best && oi < bidx)) { best = ov; bidx = oi; }
    }
    if (l16 == 0) s_cand[head] = bidx;
    __syncthreads();

    if (tid == 0) {
        int cnt[NHEAD];
        int maxv = 0;
        for (int h = 0; h < NHEAD; ++h) {
            int c = 0;
            for (int g = 0; g < NHEAD; ++g) c += (s_cand[g] == s_cand[h]);
            cnt[h] = c;
            if (c > maxv) maxv = c;
        }
        int sampled = 0;
        for (int h = NHEAD - 1; h >= 0; --h)
            if (cnt[h] == maxv) sampled = h;          // first head with mask set
        const bool merge = (maxv <= KMAX);
        for (int h = 0; h < NHEAD; ++h)
            s_replace[h] = (merge && cnt[h] == maxv) ? 1 : 0;
        s_sampled = sampled;
    }
    __syncthreads();

    const int sampled = s_sampled;

    // rewrite the 16 last rows (vectorized)
    for (int idx = tid; idx < NHEAD * S4; idx += BLKSZ) {
        const int h = idx >> 9;          // / S4
        const int f = idx & (S4 - 1);    // % S4
        const int src_h = s_replace[h] ? sampled : h;
        out[(size_t)h * HEAD4 + COPY4 + f] =
            in[(size_t)src_h * HEAD4 + COPY4 + f];
    }
}

extern "C" void kernel_launch(void* const* d_in, const int* in_sizes, int n_in,
                              void* d_out, int out_size, void* d_ws, size_t ws_size,
                              hipStream_t stream) {
    const float* in = (const float*)d_in[0];
    float* out = (float*)d_out;

    fused_policy_kernel<<<NCOPYBLK + 1, BLKSZ, 0, stream>>>(
        (const float4*)in, (float4*)out);
}